// Round 1
// baseline (413.346 us; speedup 1.0000x reference)
//
#include <hip/hip_runtime.h>
#include <hip/hip_bf16.h>
#include <stdint.h>

typedef __hip_bfloat16 bf16;
typedef __attribute__((ext_vector_type(4))) short short4v;
typedef __attribute__((ext_vector_type(8))) short short8v;
typedef __attribute__((ext_vector_type(4))) float f32x4;

#define CAT8(lo,hi) __builtin_shufflevector(lo, hi, 0,1,2,3,4,5,6,7)
#define MFMA16(a,b,c) __builtin_amdgcn_mfma_f32_16x16x32_bf16(a,b,c,0,0,0)

__device__ __forceinline__ void gload16(const void* g, void* l) {
  __builtin_amdgcn_global_load_lds((const __attribute__((address_space(1))) unsigned int*)g,
                                   (__attribute__((address_space(3))) unsigned int*)l, 16, 0, 0);
}

// ---------------- convert x (f32 -> bf16), 4 elems/thread ----------------
__global__ __launch_bounds__(256) void k_cvt_x(const float* __restrict__ in, bf16* __restrict__ out) {
  int i = blockIdx.x*256 + threadIdx.x;
  float4 v = ((const float4*)in)[i];
  bf16* o = out + (size_t)i*4;
  o[0] = __float2bfloat16(v.x); o[1] = __float2bfloat16(v.y);
  o[2] = __float2bfloat16(v.z); o[3] = __float2bfloat16(v.w);
}

// ---------------- transpose-convert: W[K][N] f32 -> Wt[N][K] bf16 ----------------
__global__ __launch_bounds__(256) void k_transpose_cvt(const float* __restrict__ W, bf16* __restrict__ Wt,
                                                       int K, int N) {
  __shared__ float ts[64][65];
  int k0 = blockIdx.y*64, n0 = blockIdx.x*64;
  int t = threadIdx.x;
  #pragma unroll
  for (int ii = 0; ii < 16; ++ii) {
    int idx = ii*256 + t; int r = idx>>6, c = idx&63;
    ts[r][c] = W[(size_t)(k0+r)*N + n0 + c];
  }
  __syncthreads();
  #pragma unroll
  for (int ii = 0; ii < 16; ++ii) {
    int idx = ii*256 + t; int r = idx>>6, c = idx&63;   // r: n-row, c: k-col
    Wt[(size_t)(n0+r)*K + k0 + c] = __float2bfloat16(ts[c][r]);
  }
}

// ---------------- GEMM: C[M][N] = A[M][K] * Bt[N][K]^T, bf16 in, f32 acc ----------------
// tile 128x128, BK=32, 256 threads (4 waves, 2x2), global_load_lds staging
__global__ __launch_bounds__(256) void k_gemm_bt(const bf16* __restrict__ A, const bf16* __restrict__ Bt,
                                                 void* __restrict__ Cp, int M, int N, int K, int ldc,
                                                 int c_bf16) {
  __shared__ bf16 Asm[128*32];
  __shared__ bf16 Bsm[128*32];
  const int t = threadIdx.x;
  const int lane = t & 63, w = t >> 6;
  const int wr = w >> 1, wc = w & 1;
  const int m0 = blockIdx.y*128, n0 = blockIdx.x*128;
  const int kb = (lane>>4)*4;
  const int l15 = lane & 15;

  f32x4 acc[4][4];
  #pragma unroll
  for (int i = 0; i < 4; ++i)
    #pragma unroll
    for (int j = 0; j < 4; ++j) acc[i][j] = 0.f;

  const char* Ab = (const char*)A;
  const char* Bb = (const char*)Bt;
  const int off = t*16;          // byte offset into tile (linear)
  const int srow = off >> 6;     // 64 B per row (32 bf16)
  const int scolb = off & 63;

  for (int k0 = 0; k0 < K; k0 += 32) {
    gload16(Ab + ((size_t)(m0+srow)*K + k0)*2 + scolb,      (char*)Asm + off);
    gload16(Ab + ((size_t)(m0+srow+64)*K + k0)*2 + scolb,   (char*)Asm + off + 4096);
    gload16(Bb + ((size_t)(n0+srow)*K + k0)*2 + scolb,      (char*)Bsm + off);
    gload16(Bb + ((size_t)(n0+srow+64)*K + k0)*2 + scolb,   (char*)Bsm + off + 4096);
    __syncthreads();

    short4v alo[4], ahi[4], blo[4], bhi[4];
    #pragma unroll
    for (int i = 0; i < 4; ++i) {
      const bf16* ap = Asm + (size_t)(wr*64 + i*16 + l15)*32;
      alo[i] = *(const short4v*)(ap + kb);
      ahi[i] = *(const short4v*)(ap + 16 + kb);
      const bf16* bp = Bsm + (size_t)(wc*64 + i*16 + l15)*32;
      blo[i] = *(const short4v*)(bp + kb);
      bhi[i] = *(const short4v*)(bp + 16 + kb);
    }
    #pragma unroll
    for (int i = 0; i < 4; ++i) {
      short8v a = CAT8(alo[i], ahi[i]);
      #pragma unroll
      for (int j = 0; j < 4; ++j) {
        short8v b = CAT8(blo[j], bhi[j]);
        acc[i][j] = MFMA16(a, b, acc[i][j]);
      }
    }
    __syncthreads();
  }

  #pragma unroll
  for (int i = 0; i < 4; ++i) {
    int row0 = m0 + wr*64 + i*16 + (lane>>4)*4;
    #pragma unroll
    for (int j = 0; j < 4; ++j) {
      int col = n0 + wc*64 + j*16 + l15;
      #pragma unroll
      for (int r = 0; r < 4; ++r) {
        if (c_bf16) ((bf16*)Cp)[(size_t)(row0+r)*ldc + col] = __float2bfloat16(acc[i][j][r]);
        else        ((float*)Cp)[(size_t)(row0+r)*ldc + col] = acc[i][j][r];
      }
    }
  }
}

// ---------------- fused RMSNorm + RoPE; V transpose-convert ----------------
// qkv: [S][3072] bf16 (q:0..2047, k:2048..2559, v:2560..3071)
// Qb: [32][S][64], Kb: [8][S][64], Vt: [8][64][S]
__global__ __launch_bounds__(256) void k_normrope(const bf16* __restrict__ qkv,
    const float* __restrict__ cosb, const float* __restrict__ sinb,
    const float* __restrict__ qg, const float* __restrict__ kg,
    bf16* __restrict__ Qb, bf16* __restrict__ Kb, bf16* __restrict__ Vt) {
  int wid = blockIdx.x*4 + (threadIdx.x>>6);
  int lane = threadIdx.x & 63;
  int s = wid / 48, r = wid - s*48;
  int col;
  if (r < 32) col = r*64;
  else if (r < 40) col = 2048 + (r-32)*64;
  else col = 2560 + (r-40)*64;
  float v = __bfloat162float(qkv[(size_t)s*3072 + col + lane]);
  if (r < 40) {
    float ss = v*v;
    #pragma unroll
    for (int o = 32; o; o >>= 1) ss += __shfl_xor(ss, o);
    float rms = rsqrtf(ss*(1.0f/64.0f) + 1e-6f);
    float g = (r < 32 ? qg : kg)[lane];
    float tn = v*rms*g;
    float other = __shfl_xor(tn, 32);
    float rot = (lane < 32) ? -other : other;
    float outv = tn*cosb[s*64+lane] + rot*sinb[s*64+lane];
    if (r < 32) Qb[((size_t)r*2048 + s)*64 + lane] = __float2bfloat16(outv);
    else        Kb[((size_t)(r-32)*2048 + s)*64 + lane] = __float2bfloat16(outv);
  } else {
    Vt[(size_t)(r-40)*64*2048 + (size_t)lane*2048 + s] = __float2bfloat16(v);
  }
}

// ---------------- causal flash attention ----------------
// Qb [32][2048][64], Kb [8][2048][64], Vt [8][64][2048] -> attnb [2048][2048] bf16
// block: 256 thr (4 waves), 64 q-rows per block (16/wave), KV tiles of 64
__global__ __launch_bounds__(256) void k_attn(const bf16* __restrict__ Qb, const bf16* __restrict__ Kb,
                                              const bf16* __restrict__ Vt, bf16* __restrict__ attnb) {
  __shared__ bf16 Ksm[64][72];
  __shared__ bf16 Vsm[64][72];
  __shared__ bf16 Plds[4][16][72];
  const int t = threadIdx.x, lane = t & 63, w = t >> 6;
  const int qb0 = blockIdx.x*64;
  const int h = blockIdx.y;
  const int kvh = h >> 2;
  const int kb = (lane>>4)*4;
  const int l15 = lane & 15;

  const bf16* Qh = Qb + (size_t)h*2048*64;
  const bf16* Kh = Kb + (size_t)kvh*2048*64;
  const bf16* Vh = Vt + (size_t)kvh*64*2048;

  const int qrow = qb0 + w*16 + l15;
  short4v qlo[2], qhi[2];
  #pragma unroll
  for (int kk = 0; kk < 2; ++kk) {
    qlo[kk] = *(const short4v*)(Qh + (size_t)qrow*64 + kk*32 + kb);
    qhi[kk] = *(const short4v*)(Qh + (size_t)qrow*64 + kk*32 + 16 + kb);
  }

  float m[4], ls[4];
  f32x4 o[4];
  #pragma unroll
  for (int r = 0; r < 4; ++r) { m[r] = -3e38f; ls[r] = 0.f; }
  #pragma unroll
  for (int j = 0; j < 4; ++j) o[j] = 0.f;

  const int nt = qb0/64 + 1;
  for (int tt = 0; tt < nt; ++tt) {
    // reg-stage K tile [64 kv][64 d] and V tile [64 d][64 s] into padded LDS
    #pragma unroll
    for (int i = 0; i < 2; ++i) {
      int idx = i*256 + t;
      int row = idx >> 3;
      int c8  = (idx & 7) * 8;
      int4 kd = *(const int4*)(Kh + ((size_t)(tt*64 + row))*64 + c8);
      *(int4*)(&Ksm[row][c8]) = kd;
      int4 vd = *(const int4*)(Vh + (size_t)row*2048 + tt*64 + c8);
      *(int4*)(&Vsm[row][c8]) = vd;
    }
    __syncthreads();

    // S = Q K^T   (C[m=q][n=kvpos])
    f32x4 sAcc[4];
    #pragma unroll
    for (int j = 0; j < 4; ++j) sAcc[j] = 0.f;
    #pragma unroll
    for (int kk = 0; kk < 2; ++kk) {
      short8v aq = CAT8(qlo[kk], qhi[kk]);
      #pragma unroll
      for (int j = 0; j < 4; ++j) {
        const bf16* kp = &Ksm[j*16 + l15][kk*32 + kb];
        short8v b = CAT8(*(const short4v*)kp, *(const short4v*)(kp + 16));
        sAcc[j] = MFMA16(aq, b, sAcc[j]);
      }
    }

    // mask + scale
    const int qrow0 = qb0 + w*16 + (lane>>4)*4;
    float sc[4][4];
    #pragma unroll
    for (int j = 0; j < 4; ++j) {
      int colj = tt*64 + j*16 + l15;
      #pragma unroll
      for (int r = 0; r < 4; ++r) {
        float x = sAcc[j][r]*0.125f;
        if (colj > qrow0 + r) x = -3e38f;
        sc[j][r] = x;
      }
    }
    // online softmax (row spread over 16 lanes x 4 regs)
    #pragma unroll
    for (int r = 0; r < 4; ++r) {
      float mx = fmaxf(fmaxf(sc[0][r], sc[1][r]), fmaxf(sc[2][r], sc[3][r]));
      #pragma unroll
      for (int o_ = 8; o_; o_ >>= 1) mx = fmaxf(mx, __shfl_xor(mx, o_));
      float mn = fmaxf(m[r], mx);
      float alpha = __expf(m[r] - mn);
      m[r] = mn;
      ls[r] *= alpha;
      #pragma unroll
      for (int j = 0; j < 4; ++j) o[j][r] *= alpha;
    }
    float rowsum[4] = {0.f, 0.f, 0.f, 0.f};
    #pragma unroll
    for (int j = 0; j < 4; ++j) {
      #pragma unroll
      for (int r = 0; r < 4; ++r) {
        float p = __expf(sc[j][r] - m[r]);
        rowsum[r] += p;
        Plds[w][(lane>>4)*4 + r][j*16 + l15] = __float2bfloat16(p);
      }
    }
    #pragma unroll
    for (int r = 0; r < 4; ++r) {
      float rs = rowsum[r];
      #pragma unroll
      for (int o_ = 8; o_; o_ >>= 1) rs += __shfl_xor(rs, o_);
      ls[r] += rs;
    }
    __syncthreads();   // P visible; also all waves done with QK^T reads

    // O += P V   (A = P [16][64], Bt = Vsm [d][kvpos])
    #pragma unroll
    for (int kk = 0; kk < 2; ++kk) {
      const bf16* pp = &Plds[w][l15][kk*32 + kb];
      short8v pa = CAT8(*(const short4v*)pp, *(const short4v*)(pp + 16));
      #pragma unroll
      for (int j = 0; j < 4; ++j) {
        const bf16* vp = &Vsm[j*16 + l15][kk*32 + kb];
        short8v bv = CAT8(*(const short4v*)vp, *(const short4v*)(vp + 16));
        o[j] = MFMA16(pa, bv, o[j]);
      }
    }
    __syncthreads();   // before restaging K/V
  }

  #pragma unroll
  for (int r = 0; r < 4; ++r) {
    float inv = 1.0f / ls[r];
    int row = qb0 + w*16 + (lane>>4)*4 + r;
    #pragma unroll
    for (int j = 0; j < 4; ++j)
      attnb[(size_t)row*2048 + h*64 + j*16 + l15] = __float2bfloat16(o[j][r]*inv);
  }
}

extern "C" void kernel_launch(void* const* d_in, const int* in_sizes, int n_in,
                              void* d_out, int out_size, void* d_ws, size_t ws_size,
                              hipStream_t stream) {
  const float* x    = (const float*)d_in[0];
  // d_in[1] = mask (unused; causal structure known)
  const float* cosb = (const float*)d_in[2];
  const float* sinb = (const float*)d_in[3];
  const float* Wq   = (const float*)d_in[4];
  const float* Wk   = (const float*)d_in[5];
  const float* Wv   = (const float*)d_in[6];
  const float* Wo   = (const float*)d_in[7];
  const float* qg   = (const float*)d_in[8];
  const float* kg   = (const float*)d_in[9];
  float* out = (float*)d_out;

  char* ws = (char*)d_ws;
  bf16* xb    = (bf16*)(ws);                    // 8 MB   [2048][2048]
  bf16* WqT   = (bf16*)(ws + 8388608);          // 8 MB   [2048][2048]
  bf16* WkT   = (bf16*)(ws + 16777216);         // 2 MB   [512][2048]  (contig after WqT)
  bf16* WvT   = (bf16*)(ws + 18874368);         // 2 MB   [512][2048]  (contig after WkT)
  bf16* WoT   = (bf16*)(ws + 20971520);         // 8 MB   [2048][2048]
  bf16* QKVb  = (bf16*)(ws + 29360128);         // 12 MB  [2048][3072]
  bf16* Qb    = (bf16*)(ws + 41943040);         // 8 MB   [32][2048][64]
  bf16* Kb    = (bf16*)(ws + 50331648);         // 2 MB   [8][2048][64]
  bf16* Vt    = (bf16*)(ws + 52428800);         // 2 MB   [8][64][2048]
  bf16* attnb = (bf16*)(ws);                    // reuse xb (dead after projections)

  // 1. convert / transpose weights + x
  k_cvt_x<<<4096, 256, 0, stream>>>(x, xb);
  k_transpose_cvt<<<dim3(32, 32), 256, 0, stream>>>(Wq, WqT, 2048, 2048);
  k_transpose_cvt<<<dim3(8, 32),  256, 0, stream>>>(Wk, WkT, 2048, 512);
  k_transpose_cvt<<<dim3(8, 32),  256, 0, stream>>>(Wv, WvT, 2048, 512);
  k_transpose_cvt<<<dim3(32, 32), 256, 0, stream>>>(Wo, WoT, 2048, 2048);

  // 2. fused QKV projection: Bt = [WqT;WkT;WvT] (contiguous, N=3072)
  k_gemm_bt<<<dim3(24, 16), 256, 0, stream>>>(xb, WqT, QKVb, 2048, 3072, 2048, 3072, 1);

  // 3. RMSNorm + RoPE (+ V transpose)
  k_normrope<<<24576, 256, 0, stream>>>(QKVb, cosb, sinb, qg, kg, Qb, Kb, Vt);

  // 4. causal flash attention
  k_attn<<<dim3(32, 32), 256, 0, stream>>>(Qb, Kb, Vt, attnb);

  // 5. output projection
  k_gemm_bt<<<dim3(16, 16), 256, 0, stream>>>(attnb, WoT, out, 2048, 2048, 2048, 2048, 0);
}

// Round 2
// 346.812 us; speedup vs baseline: 1.1918x; 1.1918x over previous
//
#include <hip/hip_runtime.h>
#include <hip/hip_bf16.h>
#include <stdint.h>

typedef __hip_bfloat16 bf16;
typedef __attribute__((ext_vector_type(4))) short short4v;
typedef __attribute__((ext_vector_type(8))) short short8v;
typedef __attribute__((ext_vector_type(4))) float f32x4;

#define CAT8(lo,hi) __builtin_shufflevector(lo, hi, 0,1,2,3,4,5,6,7)
#define MFMA16(a,b,c) __builtin_amdgcn_mfma_f32_16x16x32_bf16(a,b,c,0,0,0)

__device__ __forceinline__ void gload16(const void* g, void* l) {
  __builtin_amdgcn_global_load_lds((const __attribute__((address_space(1))) unsigned int*)g,
                                   (__attribute__((address_space(3))) unsigned int*)l, 16, 0, 0);
}

// ---------------- convert x (f32 -> bf16), 4 elems/thread ----------------
__global__ __launch_bounds__(256) void k_cvt_x(const float* __restrict__ in, bf16* __restrict__ out) {
  int i = blockIdx.x*256 + threadIdx.x;
  float4 v = ((const float4*)in)[i];
  bf16* o = out + (size_t)i*4;
  o[0] = __float2bfloat16(v.x); o[1] = __float2bfloat16(v.y);
  o[2] = __float2bfloat16(v.z); o[3] = __float2bfloat16(v.w);
}

// ---------------- transpose-convert: W[K][N] f32 -> Wt[N][K] bf16 ----------------
__global__ __launch_bounds__(256) void k_transpose_cvt(const float* __restrict__ W, bf16* __restrict__ Wt,
                                                       int K, int N) {
  __shared__ float ts[64][65];
  int k0 = blockIdx.y*64, n0 = blockIdx.x*64;
  int t = threadIdx.x;
  #pragma unroll
  for (int ii = 0; ii < 16; ++ii) {
    int idx = ii*256 + t; int r = idx>>6, c = idx&63;
    ts[r][c] = W[(size_t)(k0+r)*N + n0 + c];
  }
  __syncthreads();
  #pragma unroll
  for (int ii = 0; ii < 16; ++ii) {
    int idx = ii*256 + t; int r = idx>>6, c = idx&63;   // r: n-row, c: k-col
    Wt[(size_t)(n0+r)*K + k0 + c] = __float2bfloat16(ts[c][r]);
  }
}

// ---------------- GEMM: C[M][N] = A[M][K] * Bt[N][K]^T, bf16 in, f32 acc ----------------
// tile 128x128, BK=32, 256 threads (4 waves, 2x2), global_load_lds staging
__global__ __launch_bounds__(256) void k_gemm_bt(const bf16* __restrict__ A, const bf16* __restrict__ Bt,
                                                 void* __restrict__ Cp, int M, int N, int K, int ldc,
                                                 int c_bf16) {
  __shared__ bf16 Asm[128*32];
  __shared__ bf16 Bsm[128*32];
  const int t = threadIdx.x;
  const int lane = t & 63, w = t >> 6;
  const int wr = w >> 1, wc = w & 1;
  const int m0 = blockIdx.y*128, n0 = blockIdx.x*128;
  const int kb = (lane>>4)*4;
  const int l15 = lane & 15;

  f32x4 acc[4][4];
  #pragma unroll
  for (int i = 0; i < 4; ++i)
    #pragma unroll
    for (int j = 0; j < 4; ++j) acc[i][j] = 0.f;

  const char* Ab = (const char*)A;
  const char* Bb = (const char*)Bt;
  const int off = t*16;          // byte offset into tile (linear)
  const int srow = off >> 6;     // 64 B per row (32 bf16)
  const int scolb = off & 63;

  for (int k0 = 0; k0 < K; k0 += 32) {
    gload16(Ab + ((size_t)(m0+srow)*K + k0)*2 + scolb,      (char*)Asm + off);
    gload16(Ab + ((size_t)(m0+srow+64)*K + k0)*2 + scolb,   (char*)Asm + off + 4096);
    gload16(Bb + ((size_t)(n0+srow)*K + k0)*2 + scolb,      (char*)Bsm + off);
    gload16(Bb + ((size_t)(n0+srow+64)*K + k0)*2 + scolb,   (char*)Bsm + off + 4096);
    __syncthreads();

    short4v alo[4], ahi[4], blo[4], bhi[4];
    #pragma unroll
    for (int i = 0; i < 4; ++i) {
      const bf16* ap = Asm + (size_t)(wr*64 + i*16 + l15)*32;
      alo[i] = *(const short4v*)(ap + kb);
      ahi[i] = *(const short4v*)(ap + 16 + kb);
      const bf16* bp = Bsm + (size_t)(wc*64 + i*16 + l15)*32;
      blo[i] = *(const short4v*)(bp + kb);
      bhi[i] = *(const short4v*)(bp + 16 + kb);
    }
    #pragma unroll
    for (int i = 0; i < 4; ++i) {
      short8v a = CAT8(alo[i], ahi[i]);
      #pragma unroll
      for (int j = 0; j < 4; ++j) {
        short8v b = CAT8(blo[j], bhi[j]);
        acc[i][j] = MFMA16(a, b, acc[i][j]);
      }
    }
    __syncthreads();
  }

  #pragma unroll
  for (int i = 0; i < 4; ++i) {
    int row0 = m0 + wr*64 + i*16 + (lane>>4)*4;
    #pragma unroll
    for (int j = 0; j < 4; ++j) {
      int col = n0 + wc*64 + j*16 + l15;
      #pragma unroll
      for (int r = 0; r < 4; ++r) {
        if (c_bf16) ((bf16*)Cp)[(size_t)(row0+r)*ldc + col] = __float2bfloat16(acc[i][j][r]);
        else        ((float*)Cp)[(size_t)(row0+r)*ldc + col] = acc[i][j][r];
      }
    }
  }
}

// ---------------- fused RMSNorm + RoPE; V transpose-convert ----------------
__global__ __launch_bounds__(256) void k_normrope(const bf16* __restrict__ qkv,
    const float* __restrict__ cosb, const float* __restrict__ sinb,
    const float* __restrict__ qg, const float* __restrict__ kg,
    bf16* __restrict__ Qb, bf16* __restrict__ Kb, bf16* __restrict__ Vt) {
  int wid = blockIdx.x*4 + (threadIdx.x>>6);
  int lane = threadIdx.x & 63;
  int s = wid / 48, r = wid - s*48;
  int col;
  if (r < 32) col = r*64;
  else if (r < 40) col = 2048 + (r-32)*64;
  else col = 2560 + (r-40)*64;
  float v = __bfloat162float(qkv[(size_t)s*3072 + col + lane]);
  if (r < 40) {
    float ss = v*v;
    #pragma unroll
    for (int o = 32; o; o >>= 1) ss += __shfl_xor(ss, o);
    float rms = rsqrtf(ss*(1.0f/64.0f) + 1e-6f);
    float g = (r < 32 ? qg : kg)[lane];
    float tn = v*rms*g;
    float other = __shfl_xor(tn, 32);
    float rot = (lane < 32) ? -other : other;
    float outv = tn*cosb[s*64+lane] + rot*sinb[s*64+lane];
    if (r < 32) Qb[((size_t)r*2048 + s)*64 + lane] = __float2bfloat16(outv);
    else        Kb[((size_t)(r-32)*2048 + s)*64 + lane] = __float2bfloat16(outv);
  } else {
    Vt[(size_t)(r-40)*64*2048 + (size_t)lane*2048 + s] = __float2bfloat16(v);
  }
}

// ---------------- causal flash attention v2 ----------------
// Qb [32][2048][64], Kb [8][2048][64], Vt [8][64][2048] -> attnb [2048][2048] bf16
// 512 threads (8 waves), QBLK=128 (16 q-rows/wave), KVBLK=64
// grid: 512 blocks, flattened (head, qi) with qi DESCENDING (heavy-first)
#define SCALE2 0.18033688011f   /* (1/sqrt(64)) * log2(e) */
__global__ __launch_bounds__(512) void k_attn(const bf16* __restrict__ Qb, const bf16* __restrict__ Kb,
                                              const bf16* __restrict__ Vt, bf16* __restrict__ attnb) {
  __shared__ bf16 Ksm[64][68];
  __shared__ bf16 Vsm[64][68];
  __shared__ bf16 Plds[8][16][68];
  const int t = threadIdx.x, lane = t & 63, w = t >> 6;
  const int bid = blockIdx.x;
  const int h = bid & 31;
  const int qi = 15 - (bid >> 5);          // heavy blocks dispatched first
  const int qb0 = qi * 128;
  const int kvh = h >> 2;
  const int kb = (lane>>4)*4;
  const int l15 = lane & 15;

  const bf16* Qh = Qb + (size_t)h*2048*64;
  const bf16* Kh = Kb + (size_t)kvh*2048*64;
  const bf16* Vh = Vt + (size_t)kvh*64*2048;

  const int qrow = qb0 + w*16 + l15;
  short4v qlo[2], qhi[2];
  #pragma unroll
  for (int kk = 0; kk < 2; ++kk) {
    qlo[kk] = *(const short4v*)(Qh + (size_t)qrow*64 + kk*32 + kb);
    qhi[kk] = *(const short4v*)(Qh + (size_t)qrow*64 + kk*32 + 16 + kb);
  }

  float m[4], ls[4];
  f32x4 o[4];
  #pragma unroll
  for (int r = 0; r < 4; ++r) { m[r] = -3e38f; ls[r] = 0.f; }
  #pragma unroll
  for (int j = 0; j < 4; ++j) o[j] = 0.f;

  const int srow = t >> 3;          // staging: 512 thr, 1 int4 each for K and V
  const int sc8  = (t & 7) * 8;
  const int qrow0 = qb0 + w*16 + (lane>>4)*4;

  const int nt = 2*qi + 2;
  for (int tt = 0; tt < nt; ++tt) {
    *(int4*)(&Ksm[srow][sc8]) = *(const int4*)(Kh + ((size_t)(tt*64 + srow))*64 + sc8);
    *(int4*)(&Vsm[srow][sc8]) = *(const int4*)(Vh + (size_t)srow*2048 + tt*64 + sc8);
    __syncthreads();

    // S = Q K^T
    f32x4 sAcc[4];
    #pragma unroll
    for (int j = 0; j < 4; ++j) sAcc[j] = 0.f;
    __builtin_amdgcn_s_setprio(1);
    #pragma unroll
    for (int kk = 0; kk < 2; ++kk) {
      short8v aq = CAT8(qlo[kk], qhi[kk]);
      #pragma unroll
      for (int j = 0; j < 4; ++j) {
        const bf16* kp = &Ksm[j*16 + l15][kk*32 + kb];
        short8v b = CAT8(*(const short4v*)kp, *(const short4v*)(kp + 16));
        sAcc[j] = MFMA16(aq, b, sAcc[j]);
      }
    }
    __builtin_amdgcn_s_setprio(0);

    // scale (+ causal mask only on tiles that need it; condition wave-uniform)
    float sc[4][4];
    #pragma unroll
    for (int j = 0; j < 4; ++j)
      #pragma unroll
      for (int r = 0; r < 4; ++r) sc[j][r] = sAcc[j][r]*SCALE2;
    if (tt*64 + 63 > qb0 + w*16) {
      #pragma unroll
      for (int j = 0; j < 4; ++j) {
        int colj = tt*64 + j*16 + l15;
        #pragma unroll
        for (int r = 0; r < 4; ++r) if (colj > qrow0 + r) sc[j][r] = -3e38f;
      }
    }

    // online softmax (rows spread over 16 lanes x 4 regs), exp2 domain
    #pragma unroll
    for (int r = 0; r < 4; ++r) {
      float mx = fmaxf(fmaxf(sc[0][r], sc[1][r]), fmaxf(sc[2][r], sc[3][r]));
      #pragma unroll
      for (int o_ = 8; o_; o_ >>= 1) mx = fmaxf(mx, __shfl_xor(mx, o_));
      float mn = fmaxf(m[r], mx);
      float alpha = exp2f(m[r] - mn);
      m[r] = mn;
      ls[r] *= alpha;
      #pragma unroll
      for (int j = 0; j < 4; ++j) o[j][r] *= alpha;
    }
    float rowsum[4] = {0.f, 0.f, 0.f, 0.f};
    #pragma unroll
    for (int j = 0; j < 4; ++j) {
      #pragma unroll
      for (int r = 0; r < 4; ++r) {
        float p = exp2f(sc[j][r] - m[r]);
        rowsum[r] += p;
        Plds[w][(lane>>4)*4 + r][j*16 + l15] = __float2bfloat16(p);
      }
    }
    #pragma unroll
    for (int r = 0; r < 4; ++r) {
      float rs = rowsum[r];
      #pragma unroll
      for (int o_ = 8; o_; o_ >>= 1) rs += __shfl_xor(rs, o_);
      ls[r] += rs;
    }

    // O += P V   (Plds[w] is wave-private: no barrier needed, lgkmcnt suffices)
    __builtin_amdgcn_s_setprio(1);
    #pragma unroll
    for (int kk = 0; kk < 2; ++kk) {
      const bf16* pp = &Plds[w][l15][kk*32 + kb];
      short8v pa = CAT8(*(const short4v*)pp, *(const short4v*)(pp + 16));
      #pragma unroll
      for (int j = 0; j < 4; ++j) {
        const bf16* vp = &Vsm[j*16 + l15][kk*32 + kb];
        short8v bv = CAT8(*(const short4v*)vp, *(const short4v*)(vp + 16));
        o[j] = MFMA16(pa, bv, o[j]);
      }
    }
    __builtin_amdgcn_s_setprio(0);
    __syncthreads();   // all waves done reading K/V before restaging
  }

  #pragma unroll
  for (int r = 0; r < 4; ++r) {
    float inv = 1.0f / ls[r];
    int row = qb0 + w*16 + (lane>>4)*4 + r;
    #pragma unroll
    for (int j = 0; j < 4; ++j)
      attnb[(size_t)row*2048 + h*64 + j*16 + l15] = __float2bfloat16(o[j][r]*inv);
  }
}

extern "C" void kernel_launch(void* const* d_in, const int* in_sizes, int n_in,
                              void* d_out, int out_size, void* d_ws, size_t ws_size,
                              hipStream_t stream) {
  const float* x    = (const float*)d_in[0];
  const float* cosb = (const float*)d_in[2];
  const float* sinb = (const float*)d_in[3];
  const float* Wq   = (const float*)d_in[4];
  const float* Wk   = (const float*)d_in[5];
  const float* Wv   = (const float*)d_in[6];
  const float* Wo   = (const float*)d_in[7];
  const float* qg   = (const float*)d_in[8];
  const float* kg   = (const float*)d_in[9];
  float* out = (float*)d_out;

  char* ws = (char*)d_ws;
  bf16* xb    = (bf16*)(ws);                    // 8 MB   [2048][2048]
  bf16* WqT   = (bf16*)(ws + 8388608);          // 8 MB   [2048][2048]
  bf16* WkT   = (bf16*)(ws + 16777216);         // 2 MB   [512][2048]
  bf16* WvT   = (bf16*)(ws + 18874368);         // 2 MB   [512][2048]
  bf16* WoT   = (bf16*)(ws + 20971520);         // 8 MB   [2048][2048]
  bf16* QKVb  = (bf16*)(ws + 29360128);         // 12 MB  [2048][3072]
  bf16* Qb    = (bf16*)(ws + 41943040);         // 8 MB   [32][2048][64]
  bf16* Kb    = (bf16*)(ws + 50331648);         // 2 MB   [8][2048][64]
  bf16* Vt    = (bf16*)(ws + 52428800);         // 2 MB   [8][64][2048]
  bf16* attnb = (bf16*)(ws);                    // reuse xb (dead after projections)

  k_cvt_x<<<4096, 256, 0, stream>>>(x, xb);
  k_transpose_cvt<<<dim3(32, 32), 256, 0, stream>>>(Wq, WqT, 2048, 2048);
  k_transpose_cvt<<<dim3(8, 32),  256, 0, stream>>>(Wk, WkT, 2048, 512);
  k_transpose_cvt<<<dim3(8, 32),  256, 0, stream>>>(Wv, WvT, 2048, 512);
  k_transpose_cvt<<<dim3(32, 32), 256, 0, stream>>>(Wo, WoT, 2048, 2048);

  k_gemm_bt<<<dim3(24, 16), 256, 0, stream>>>(xb, WqT, QKVb, 2048, 3072, 2048, 3072, 1);
  k_normrope<<<24576, 256, 0, stream>>>(QKVb, cosb, sinb, qg, kg, Qb, Kb, Vt);
  k_attn<<<512, 512, 0, stream>>>(Qb, Kb, Vt, attnb);
  k_gemm_bt<<<dim3(16, 16), 256, 0, stream>>>(attnb, WoT, out, 2048, 2048, 2048, 2048, 0);
}